// Round 13
// baseline (7148.094 us; speedup 1.0000x reference)
//
#include <hip/hip_runtime.h>

// LSTMAutoEncoder: B=64, T=512, H=512, F=32.
// Dead-code: only encoder L0 (final h,c) and decoder L0 feed the output:
//   out[:, t, :] = h_dec0_before_step(511-t) @ W_out^T + b_out
// -> 1024 sequential cell steps; batch in 8 pods of 8 rows x 32 blocks.
//
// Round 13 = round 12 with the prologue compile fix (gp scoping).
// ZERO barriers, no Gr planes, no LDS reduce. Wave w owns hidden
// j0+4w..+4 (all 4 gate types) over FULL K: lane=(ks 0..15, jl 0..3), weights
// 4x(8 f4v + float2) = 136 f32. K-reduce = in-wave shfl_xor butterfly; then
// static-select b=ks, activate, publish tagged {f32 h|u32 s+1} from registers.
// U is block-shared parity-2, skewed (slice stride 36, row stride 580 -> all
// LDS 2-way max). Staging = r11's wave-private tagged gather (16 u64/lane,
// early-issue evens, fast retry) in order 0,2,4,6|1,3,5,7 with TWO intra-CU
// LDS flags per wave per step (even/odd half); GEMM sub-round r<4 reads only
// even sub-chunks, r>=4 odd. Parity-2 race-free by induction: stage(s+2) >
// GEMM(s+1) > all flags(s+1) > all GEMM(s) reads of the same parity plane.

#define BB   64
#define TT   512
#define HH   512
#define FF   32
#define PODS 8
#define BT   8
#define GBLK 32
#define NTHR 256
#define NBLK (PODS * BT * 4)       // 256
#define URS  580                   // U row stride (16 slices x 36 + 4 skew)
#define UPF  (BT * URS)            // 4640 floats per parity
#define UXS  34                    // UX row stride
#define PUB_U64 (2 * PODS * BT * HH)   // 65536 u64 (512 KB in d_ws)

typedef float f4v __attribute__((ext_vector_type(4)));
typedef unsigned long long u64;

__device__ __forceinline__ float sigmf(float x)    { return 1.f / (1.f + __expf(-x)); }
__device__ __forceinline__ float tanhfast(float x) { return 1.f - 2.f / (__expf(2.f * x) + 1.f); }

__global__ void init_ws_kernel(u64* pub) {
  const int i = blockIdx.x * blockDim.x + threadIdx.x;
  if (i < PUB_U64) pub[i] = 0ull;   // h = 0.0f, tag = 0 (both parities)
}

#define LDU64(P) __hip_atomic_load((P), __ATOMIC_RELAXED, __HIP_MEMORY_SCOPE_AGENT)
#define FL_LD(P) __hip_atomic_load((P), __ATOMIC_ACQUIRE, __HIP_MEMORY_SCOPE_WORKGROUP)
#define FL_ST(P,V) __hip_atomic_store((P), (V), __ATOMIC_RELEASE, __HIP_MEMORY_SCOPE_WORKGROUP)

// Issue chunk Q's two tagged loads (cols 16Q+2sub, +1) into slot SL.
#define ISSUE(SL, Q) do {                                                      \
    va[SL] = LDU64(gp + 16 * (Q));                                             \
    vb[SL] = LDU64(gp + 16 * (Q) + 1);                                         \
  } while (0)

// Wait slot SL (chunk Q) fresh (tags >= s), fast retry (sleep after 2 rounds),
// stage both cols with one 8B LDS write at the skewed address.
#define STG(SL, Q) do {                                                        \
    int tries = 0;                                                             \
    while ((unsigned)(va[SL] >> 32) < us || (unsigned)(vb[SL] >> 32) < us) {   \
      if (++tries > 2) __builtin_amdgcn_s_sleep(1);                            \
      va[SL] = LDU64(gp + 16 * (Q));                                           \
      vb[SL] = LDU64(gp + 16 * (Q) + 1);                                       \
    }                                                                          \
    float2 st_;                                                                \
    st_.x = __uint_as_float((unsigned)va[SL]);                                 \
    st_.y = __uint_as_float((unsigned)vb[SL]);                                 \
    *(float2*)&Uw[36 * ((Q) >> 1) + ((Q) & 1) * 16] = st_;                     \
  } while (0)

// GEMM sub-round R: lane's cols [32ks+4R, +4) x 8 rows x 4 gate types.
#define SUBR(R) do {                                                           \
    _Pragma("unroll")                                                          \
    for (int b = 0; b < 8; ++b) {                                              \
      const f4v u = *(const f4v*)(Ub + b * URS + 4 * (R));                     \
      _Pragma("unroll")                                                        \
      for (int m = 0; m < 4; ++m)                                              \
        acc[m][b] += u[0] * wv[m][R][0] + u[1] * wv[m][R][1]                   \
                   + u[2] * wv[m][R][2] + u[3] * wv[m][R][3];                  \
    }                                                                          \
  } while (0)

#define SPIN_FLAGS(HALF) do {                                                  \
    int f0_, f1_, f2_, f3_;                                                    \
    do {                                                                       \
      f0_ = FL_LD(&fls[fb + 0 + (HALF)]); f1_ = FL_LD(&fls[fb + 2 + (HALF)]);  \
      f2_ = FL_LD(&fls[fb + 4 + (HALF)]); f3_ = FL_LD(&fls[fb + 6 + (HALF)]);  \
    } while (f0_ < s || f1_ < s || f2_ < s || f3_ < s);                        \
  } while (0)

__global__ void __launch_bounds__(NTHR, 1)
lstm_ae_kernel(const float* __restrict__ x,
               const float* __restrict__ eWih, const float* __restrict__ eWhh,
               const float* __restrict__ ebih, const float* __restrict__ ebhh,
               const float* __restrict__ dWih, const float* __restrict__ dWhh,
               const float* __restrict__ dbih, const float* __restrict__ dbhh,
               const float* __restrict__ Wo,  const float* __restrict__ bo,
               float* __restrict__ out, u64* __restrict__ pub)
{
  __shared__ float U[2 * UPF];          // [2][8][URS] skewed h staging (37 KB)
  __shared__ float UX[4 * BT * UXS];    // [4][8][34]  per-wave x slice
  __shared__ int   fls[16];             // [2 par][4 waves][2 halves]

  const int tid = threadIdx.x;
  const int blk = blockIdx.x;
  const int pod = blk & (PODS - 1);
  const int gb  = blk >> 3;            // 0..31 within pod
  const int b0  = pod * BT;
  const int j0  = gb * 16;

  const int w    = tid >> 6;           // wave: stages cols [128w,+128),
  const int lane = tid & 63;           //       computes hidden j0+4w..+4
  const int row  = lane >> 3;          // staging: batch row
  const int sub  = lane & 7;           // staging: col-pair offset
  const int ks   = lane >> 2;          // gemm: K-slice 0..15 (cols [32ks,+32))
  const int jl   = lane & 3;           // gemm: hidden sub-index
  const int jglob = j0 + 4 * w + jl;

  // Weights: 4 gate types x (8 f4v over [32ks,+32) + float2 x-cols {2ks,+1}).
  f4v   wv[4][8];
  float2 wx[4];
  float bias[4];
  {
    #pragma unroll
    for (int m = 0; m < 4; ++m) {
      const int g = m * HH + jglob;
      #pragma unroll
      for (int q = 0; q < 8; ++q)
        wv[m][q] = *(const f4v*)&eWhh[g * HH + 32 * ks + 4 * q];
      wx[m]   = *(const float2*)&eWih[g * FF + 2 * ks];
      bias[m] = ebih[g] + ebhh[g];
    }
  }

  if (tid < 16) fls[tid] = -1;
  __syncthreads();                     // once, outside the loop

  float c_reg = 0.f;                   // lanes ks<8 own c[b=ks][jglob]
  u64 va[8], vb[8];
  {                                    // prologue: issue evens for s=0
    const u64* gp = pub + (size_t)pod * (BT * HH) + row * HH + 128 * w + 2 * sub;
    ISSUE(0, 0); ISSUE(1, 2); ISSUE(2, 4); ISSUE(3, 6);
  }

  #pragma unroll 1
  for (int phase = 0; phase < 2; ++phase) {
    #pragma unroll 1
    for (int step = 0; step < TT; ++step) {
      const int s = phase * TT + step;
      const unsigned us = (unsigned)s;
      const int t = phase ? (TT - 1 - step) : step;
      const u64* prd = pub + (size_t)((s & 1) * PODS + pod) * (BT * HH);
      u64*       pwr = pub + (size_t)(((s + 1) & 1) * PODS + pod) * (BT * HH);
      float* Ucur = U + (s & 1) * UPF;
      const int fb = (s & 1) * 8;
      const u64* gp = prd + row * HH + 128 * w + 2 * sub;
      float* Uw  = Ucur + row * URS + 144 * w + 2 * sub;
      float* UXw = UX + w * (BT * UXS);

      // ---- stage own x slice (global latency hides under even waits) ----
      {
        const f4v xv = *(const f4v*)&x[((size_t)(b0 + row) * TT + t) * FF + 4 * sub];
        *(f4v*)&UXw[row * UXS + 4 * sub] = xv;
      }
      // issue odd chunks
      ISSUE(4, 1); ISSUE(5, 3); ISSUE(6, 5); ISSUE(7, 7);

      // ---- stage even half (early-issued), flag ----
      STG(0, 0); STG(1, 2); STG(2, 4); STG(3, 6);
      asm volatile("s_waitcnt lgkmcnt(0)" ::: "memory");
      if (lane == 0) FL_ST(&fls[fb + w * 2 + 0], s);

      float acc[4][8];
      #pragma unroll
      for (int m = 0; m < 4; ++m)
        #pragma unroll
        for (int b = 0; b < 8; ++b) acc[m][b] = (ks == 0) ? bias[m] : 0.f;

      SPIN_FLAGS(0);
      const float* Ub = Ucur + 36 * ks;

      // ---- even sub-rounds, interleaved with odd staging ----
      SUBR(0); STG(4, 1);
      SUBR(1); STG(5, 3);
      SUBR(2); STG(6, 5);
      SUBR(3); STG(7, 7);
      asm volatile("s_waitcnt lgkmcnt(0)" ::: "memory");
      if (lane == 0) FL_ST(&fls[fb + w * 2 + 1], s);
      SPIN_FLAGS(1);
      SUBR(4); SUBR(5); SUBR(6); SUBR(7);

      // ---- x part ----
      #pragma unroll
      for (int b = 0; b < 8; ++b) {
        const float2 ux = *(const float2*)&UXw[b * UXS + 2 * ks];
        #pragma unroll
        for (int m = 0; m < 4; ++m)
          acc[m][b] += ux.x * wx[m].x + ux.y * wx[m].y;
      }

      // ---- in-wave K reduction: butterfly over ks (lane bits 2..5) ----
      #pragma unroll
      for (int m = 0; m < 4; ++m)
        #pragma unroll
        for (int b = 0; b < 8; ++b) {
          acc[m][b] += __shfl_xor(acc[m][b], 4);
          acc[m][b] += __shfl_xor(acc[m][b], 8);
          acc[m][b] += __shfl_xor(acc[m][b], 16);
          acc[m][b] += __shfl_xor(acc[m][b], 32);
        }

      // ---- lanes ks<8: batch row b=ks -> activation, c update, publish ----
      if (ks < 8) {
        float gi = acc[0][0], gf = acc[1][0], gg = acc[2][0], go = acc[3][0];
        #pragma unroll
        for (int b = 1; b < 8; ++b)
          if (ks == b) { gi = acc[0][b]; gf = acc[1][b]; gg = acc[2][b]; go = acc[3][b]; }
        const float c2 = sigmf(gf) * c_reg + sigmf(gi) * tanhfast(gg);
        const float h2 = sigmf(go) * tanhfast(c2);
        c_reg = c2;
        const u64 pk = ((u64)(unsigned)(s + 1) << 32) | (u64)__float_as_uint(h2);
        __hip_atomic_store(&pwr[ks * HH + jglob], pk,
                           __ATOMIC_RELAXED, __HIP_MEMORY_SCOPE_AGENT);
      }

      // ---- decoder out-projection: direct (no LDS, no combiner).
      // U[par] fully staged (flags passed); uses pre-update h(t). ----
      if (phase) {
        const int orow = 2 * w + (lane >> 5);   // this wave: rows 2w, 2w+1
        const int c16  = lane & 31;             // 16-col slice
        const float* Ur = Ucur + orow * URS + 36 * (c16 >> 1) + (c16 & 1) * 16;
        const float* Wr = Wo + gb * HH + c16 * 16;
        float pj = 0.f;
        #pragma unroll
        for (int k = 0; k < 16; k += 4) {
          const f4v u  = *(const f4v*)(Ur + k);
          const f4v wo = *(const f4v*)(Wr + k);
          pj += u[0]*wo[0] + u[1]*wo[1] + u[2]*wo[2] + u[3]*wo[3];
        }
        pj += __shfl_xor(pj, 1);
        pj += __shfl_xor(pj, 2);
        pj += __shfl_xor(pj, 4);
        pj += __shfl_xor(pj, 8);
        pj += __shfl_xor(pj, 16);
        if ((lane & 31) == 0)
          out[((size_t)(b0 + orow) * TT + t) * FF + gb] = pj + bo[gb];
      }

      // ---- early-issue even chunks for step s+1 (next parity plane) ----
      {
        const u64* gp = (const u64*)pwr + row * HH + 128 * w + 2 * sub;
        ISSUE(0, 0); ISSUE(1, 2); ISSUE(2, 4); ISSUE(3, 6);
        asm volatile("" ::: "memory");
      }
    }
    if (phase == 0) {  // encoder done: swap register weights to decoder
      #pragma unroll
      for (int m = 0; m < 4; ++m) {
        const int g = m * HH + jglob;
        #pragma unroll
        for (int q = 0; q < 8; ++q)
          wv[m][q] = *(const f4v*)&dWhh[g * HH + 32 * ks + 4 * q];
        wx[m]   = *(const float2*)&dWih[g * FF + 2 * ks];
        bias[m] = dbih[g] + dbhh[g];
      }
    }
  }
}

extern "C" void kernel_launch(void* const* d_in, const int* in_sizes, int n_in,
                              void* d_out, int out_size, void* d_ws, size_t ws_size,
                              hipStream_t stream) {
  const float* x    = (const float*)d_in[0];
  const float* eWih = (const float*)d_in[1];   // enc_Wih0 [2048,32]
  const float* eWhh = (const float*)d_in[2];   // enc_Whh0 [2048,512]
  const float* ebih = (const float*)d_in[3];
  const float* ebhh = (const float*)d_in[4];
  // d_in[5..8] enc layer 1: dead (only feeds dead decoder layer 1)
  const float* dWih = (const float*)d_in[9];   // dec_Wih0
  const float* dWhh = (const float*)d_in[10];  // dec_Whh0
  const float* dbih = (const float*)d_in[11];
  const float* dbhh = (const float*)d_in[12];
  // d_in[13..16] dec layer 1: dead (hB/cB never reach outs)
  const float* Wo   = (const float*)d_in[17];  // [32,512]
  const float* bo   = (const float*)d_in[18];  // [32]
  float* out = (float*)d_out;

  u64* pubbuf = (u64*)d_ws;                    // [2][PODS][BT][HH] tagged h

  init_ws_kernel<<<dim3((PUB_U64 + NTHR - 1) / NTHR), dim3(NTHR), 0, stream>>>(pubbuf);
  lstm_ae_kernel<<<dim3(NBLK), dim3(NTHR), 0, stream>>>(
      x, eWih, eWhh, ebih, ebhh, dWih, dWhh, dbih, dbhh, Wo, bo,
      out, pubbuf);
}

// Round 14
// 5688.757 us; speedup vs baseline: 1.2565x; 1.2565x over previous
//
#include <hip/hip_runtime.h>

// LSTMAutoEncoder: B=64, T=512, H=512, F=32.
// Dead-code: only encoder L0 (final h,c) and decoder L0 feed the output:
//   out[:, t, :] = h_dec0_before_step(511-t) @ W_out^T + b_out
// -> 1024 sequential cell steps; batch in 8 pods of 8 rows x 32 blocks.
//
// Round 14 = round 11 skeleton (proven best: wave-private 8-chunk gather->FMA
// pipeline, early issue, ONE barrier, Gr reduce, deferred out-proj) +:
//  - MANTISSA-TAG u32 publishes: h's low mantissa byte carries (s+1)&255.
//    One u32 store per h (was u64); gather = 8 u64 loads/lane, each load
//    fetches 2 self-validating columns. Traffic and gather insts halved.
//    Tag '==' is exact: skew < 2 steps (publish is post-BAR, r11 invariant)
//    << 256-step wrap. Injected error <= 255*2^-24 ~ 1.5e-5 per h.
//  - PACKED FP32: inner product in float2 (v_pk_fma_f32) -> GEMM insts halve.
// r13's lessons applied: keep the hardware barrier (flag spins lose, twice
// confirmed); ignore Gr bank conflicts (not on critical path, twice confirmed).

#define BB   64
#define TT   512
#define HH   512
#define FF   32
#define KP   548              // U row stride (floats): 512 h + 32 x + pad
#define PODS 8
#define BT   8                // batch rows per pod
#define GBLK 32               // blocks per pod
#define JT   16               // hidden indices per block
#define NTHR 256
#define NBLK (PODS * GBLK)
#define GRS  66               // Gr batch-row stride (64 gates + 2 pad)
#define GPL  (BT * GRS + 8)   // 536: per-ks plane stride
#define GRF  (16 * GPL)       // 8576 floats per parity
#define U_FLOATS  (BT * KP)   // 4384
#define OP3F 32               // [4 waves][8 rows] out-proj partials per slot
#define LDS_FLOATS (U_FLOATS + 2 * GRF + 3 * OP3F)   // 21632 (86.5 KB)
#define LDS_BYTES  (LDS_FLOATS * 4)
#define PUB_U32  (2 * PODS * BT * HH)   // 65536 u32 (256 KB in d_ws)

typedef float f4v __attribute__((ext_vector_type(4)));
typedef float f2v __attribute__((ext_vector_type(2)));
typedef unsigned long long u64;
typedef unsigned int u32;

__device__ __forceinline__ float sigmf(float x)    { return 1.f / (1.f + __expf(-x)); }
__device__ __forceinline__ float tanhfast(float x) { return 1.f - 2.f / (__expf(2.f * x) + 1.f); }

// Thread (w, kap, gt) owns, for every chunk q=0..7, cols [128w+16q+4kap, +4)
// of the 4 gate rows {m*HH + j0 + gt} plus x-cols {8w+2kap, +1}.
// Stored as float2 pairs for v_pk_fma_f32.
__device__ __forceinline__ void load_w(
    const float* __restrict__ Wih, const float* __restrict__ Whh,
    const float* __restrict__ bih, const float* __restrict__ bhh,
    int j0, int w, int kap, int gt,
    f2v w01[4][8], f2v w23[4][8], f2v wxv[4], float bias[4])
{
  #pragma unroll
  for (int m = 0; m < 4; ++m) {
    const int g = m * HH + j0 + gt;
    #pragma unroll
    for (int q = 0; q < 8; ++q) {
      const f4v tw = *(const f4v*)&Whh[g * HH + w * 128 + q * 16 + kap * 4];
      f2v a; a[0] = tw[0]; a[1] = tw[1]; w01[m][q] = a;
      f2v b; b[0] = tw[2]; b[1] = tw[3]; w23[m][q] = b;
    }
    wxv[m]  = *(const f2v*)&Wih[g * FF + w * 8 + kap * 2];
    bias[m] = bih[g] + bhh[g];
  }
}

__global__ void init_ws_kernel(u32* pub) {
  const int i = blockIdx.x * blockDim.x + threadIdx.x;
  if (i < PUB_U32) pub[i] = 0u;   // h = 0.0f, tag byte = 0 (both parities)
}

#define LDU64(P) __hip_atomic_load((P), __ATOMIC_RELAXED, __HIP_MEMORY_SCOPE_AGENT)

// Issue chunk Q's single u64 load (2 tagged u32 cols 16Q+2sub, +1) from base GP.
#define ISSUE(Q, GP) v[Q] = LDU64((const u64*)((GP) + 16 * (Q)))

// Wait chunk Q fresh (both halves' tag byte == tg), fast retry (sleep after 2
// rounds), strip tags, stage both cols with one 8B LDS write.
#define WAITCH(Q) do {                                                         \
    unsigned lo_ = (unsigned)v[Q], hi_ = (unsigned)(v[Q] >> 32);               \
    int tries = 0;                                                             \
    while ((lo_ & 255u) != tg || (hi_ & 255u) != tg) {                         \
      if (++tries > 2) __builtin_amdgcn_s_sleep(1);                            \
      v[Q] = LDU64((const u64*)(gp + 16 * (Q)));                               \
      lo_ = (unsigned)v[Q]; hi_ = (unsigned)(v[Q] >> 32);                      \
    }                                                                          \
    float2 st_;                                                                \
    st_.x = __uint_as_float(lo_ & ~255u);                                      \
    st_.y = __uint_as_float(hi_ & ~255u);                                      \
    *(float2*)&Us[16 * (Q)] = st_;                                             \
  } while (0)

// FMA on chunk Q: 8 rows x 4 cols x 4 gate types, packed float2 (pk_fma).
#define FMACHUNK(Q) do {                                                       \
    asm volatile("" ::: "memory");                                             \
    _Pragma("unroll")                                                          \
    for (int b = 0; b < 8; ++b) {                                              \
      const f4v u = *(const f4v*)&U[b * KP + w * 128 + 16 * (Q) + 4 * kap];    \
      f2v u01; u01[0] = u[0]; u01[1] = u[1];                                   \
      f2v u23; u23[0] = u[2]; u23[1] = u[3];                                   \
      _Pragma("unroll")                                                        \
      for (int m = 0; m < 4; ++m)                                              \
        acc2[m][b] += u01 * w01[m][Q] + u23 * w23[m][Q];                       \
    }                                                                          \
  } while (0)

__global__ void __launch_bounds__(NTHR, 1)
lstm_ae_kernel(const float* __restrict__ x,
               const float* __restrict__ eWih, const float* __restrict__ eWhh,
               const float* __restrict__ ebih, const float* __restrict__ ebhh,
               const float* __restrict__ dWih, const float* __restrict__ dWhh,
               const float* __restrict__ dbih, const float* __restrict__ dbhh,
               const float* __restrict__ Wo,  const float* __restrict__ bo,
               float* __restrict__ out, u32* __restrict__ pub)
{
  extern __shared__ float lds[];
  float* U   = lds;                      // [BT][KP]      h | x_t (wave-private cols)
  float* Gr  = lds + U_FLOATS;           // [2][16][GPL]  K-split partials (parity)
  float* OP3 = lds + U_FLOATS + 2 * GRF; // [3][4][8]     out-proj partials (mod-3)

  const int tid = threadIdx.x;
  const int blk = blockIdx.x;
  const int pod = blk & (PODS - 1);
  const int gb  = blk >> 3;          // 0..31 within pod
  const int b0  = pod * BT;
  const int j0  = gb * JT;

  const int w    = tid >> 6;         // wave 0..3: owns h cols [128w,128w+128)
  const int lane = tid & 63;
  const int row  = lane >> 3;        // batch row 0..7
  const int sub  = lane & 7;         // col-pair sub-offset within chunk

  const int ks  = tid >> 4;          // K-slice id 0..15 (Gr plane index)
  const int kap = ks & 3;            // chunk-column group 0..3
  const int gt  = tid & 15;          // hidden index within block

  // Update mapping (static across steps -> c stays in a register).
  const bool upd = tid < BT * JT;            // waves 0-1
  const int  ub  = tid >> 4, ujl = tid & 15;
  float c_reg = 0.f;

  f2v   w01[4][8], w23[4][8], wxv[4];
  float bias[4];
  load_w(eWih, eWhh, ebih, ebhh, j0, w, kap, gt, w01, w23, wxv, bias);

  // Gather state persists across iterations (early-issued chunks 0-3).
  u64 v[8];
  {
    const u32* gp = pub + (size_t)pod * (BT * HH) + row * HH + 128 * w + 2 * sub;
    ISSUE(0, gp); ISSUE(1, gp); ISSUE(2, gp); ISSUE(3, gp);
  }

  #pragma unroll 1
  for (int phase = 0; phase < 2; ++phase) {
    #pragma unroll 1
    for (int step = 0; step < TT; ++step) {
      const int s = phase * TT + step;       // global step 0..1023
      const unsigned tg = (unsigned)(s & 255);
      const int t = phase ? (TT - 1 - step) : step;
      const u32* prd = pub + (size_t)((s & 1) * PODS + pod) * (BT * HH);
      u32*       pwr = pub + (size_t)(((s + 1) & 1) * PODS + pod) * (BT * HH);
      float* Grp = Gr + (s & 1) * GRF;

      // ---- stage this wave's x slice (latency overlaps first wait) ----
      U[row * KP + HH + w * 8 + sub] =
          x[((size_t)(b0 + row) * TT + t) * FF + w * 8 + sub];

      float2 accinit; accinit.x = 0.f; accinit.y = 0.f;
      f2v acc2[4][8];
      #pragma unroll
      for (int m = 0; m < 4; ++m)
        #pragma unroll
        for (int b = 0; b < 8; ++b) {
          f2v z; z[0] = (ks == 0) ? bias[m] : 0.f; z[1] = 0.f;
          acc2[m][b] = z;
        }

      // ---- 8-chunk gather->FMA pipeline (chunks 0-3 issued LAST step) ----
      const u32* gp = prd + row * HH + 128 * w + 2 * sub;
      float*     Us = U + row * KP + 128 * w + 2 * sub;

      WAITCH(0); ISSUE(4, gp); FMACHUNK(0);
      WAITCH(1); ISSUE(5, gp); FMACHUNK(1);
      WAITCH(2); ISSUE(6, gp); FMACHUNK(2);
      WAITCH(3); ISSUE(7, gp); FMACHUNK(3);
      WAITCH(4); FMACHUNK(4);
      WAITCH(5); FMACHUNK(5);
      WAITCH(6); FMACHUNK(6);
      WAITCH(7); FMACHUNK(7);

      // ---- x part (packed) ----
      #pragma unroll
      for (int b = 0; b < 8; ++b) {
        const f2v ux = *(const f2v*)&U[b * KP + HH + w * 8 + 2 * kap];
        #pragma unroll
        for (int m = 0; m < 4; ++m)
          acc2[m][b] += ux * wxv[m];
      }
      {
        float* Gw = Grp + ks * GPL + gt;
        #pragma unroll
        for (int b = 0; b < 8; ++b)
          #pragma unroll
          for (int m = 0; m < 4; ++m)
            Gw[b * GRS + m * 16] = acc2[m][b][0] + acc2[m][b][1];
      }
      __syncthreads();   // BAR A (the only barrier): Gr complete

      // ---- reduce 16 K-split partials, activations, update, tagged publish ----
      if (upd) {
        const float* g0 = Grp + ub * GRS + ujl;
        float si = 0.f, sf = 0.f, sg = 0.f, so = 0.f;
        #pragma unroll
        for (int q = 0; q < 16; ++q) {
          const float* g = g0 + q * GPL;
          si += g[0]; sf += g[16]; sg += g[32]; so += g[48];
        }
        const float c2 = sigmf(sf) * c_reg + sigmf(si) * tanhfast(sg);
        const float h2 = sigmf(so) * tanhfast(c2);
        c_reg = c2;
        // mantissa-tag publish: low byte of the f32 carries (s+1)&255
        const unsigned pk = (__float_as_uint(h2) & ~255u)
                          | ((unsigned)(s + 1) & 255u);
        __hip_atomic_store(&pwr[ub * HH + j0 + ujl], pk,
                           __ATOMIC_RELAXED, __HIP_MEMORY_SCOPE_AGENT);
      }

      // ---- decoder out-projection, POST-barrier (overlaps reduce/publish).
      // Partial over this wave's own 128 U cols (pre-update h(t), faithful),
      // shfl-reduced over sub -> 8 floats/wave into OP3[s%3]; combined one
      // step later (BAR A of s+1 orders the writes; (s+1)%3 != (s-1)%3). ----
      if (phase) {
        const float* wrow = Wo + gb * HH + w * 128 + sub * 16;
        const float* urow = U + row * KP + w * 128 + sub * 16;
        float pj = 0.f;
        #pragma unroll
        for (int k = 0; k < 16; k += 4) {
          const f4v wvv = *(const f4v*)(wrow + k);
          const f4v uvv = *(const f4v*)(urow + k);
          pj += uvv[0] * wvv[0] + uvv[1] * wvv[1] + uvv[2] * wvv[2] + uvv[3] * wvv[3];
        }
        pj += __shfl_xor(pj, 1);
        pj += __shfl_xor(pj, 2);
        pj += __shfl_xor(pj, 4);
        if (sub == 0) OP3[(s % 3) * OP3F + w * 8 + row] = pj;
        // combine PREVIOUS decode step (t_prev = t+1)
        if (step > 0 && tid >= 192 && tid < 200) {
          const int b = tid - 192;
          const float* op = OP3 + ((s - 1) % 3) * OP3F + b;
          const float sm = op[0] + op[8] + op[16] + op[24];
          out[((size_t)(b0 + b) * TT + (t + 1)) * FF + gb] = sm + bo[gb];
        }
      }

      // ---- EARLY ISSUE: chunks 0-3 of step s+1 (next parity = pwr plane).
      // First MALL round trip flies during loop overhead / x staging; stale
      // arrivals simply retry in WAITCH. Compiler barrier pins placement. ----
      {
        const u32* gpn = (const u32*)pwr + row * HH + 128 * w + 2 * sub;
        ISSUE(0, gpn); ISSUE(1, gpn); ISSUE(2, gpn); ISSUE(3, gpn);
        asm volatile("" ::: "memory");
      }
    }
    if (phase == 0)  // encoder done: swap register weights to decoder
      load_w(dWih, dWhh, dbih, dbhh, j0, w, kap, gt, w01, w23, wxv, bias);
  }

  // ---- epilogue: combine the final decode step's out-proj (t = 0) ----
  __syncthreads();
  if (tid >= 192 && tid < 200) {
    const int b = tid - 192;
    const float* op = OP3 + ((2 * TT - 1) % 3) * OP3F + b;
    const float sm = op[0] + op[8] + op[16] + op[24];
    out[((size_t)(b0 + b) * TT + 0) * FF + gb] = sm + bo[gb];
  }
}

extern "C" void kernel_launch(void* const* d_in, const int* in_sizes, int n_in,
                              void* d_out, int out_size, void* d_ws, size_t ws_size,
                              hipStream_t stream) {
  const float* x    = (const float*)d_in[0];
  const float* eWih = (const float*)d_in[1];   // enc_Wih0 [2048,32]
  const float* eWhh = (const float*)d_in[2];   // enc_Whh0 [2048,512]
  const float* ebih = (const float*)d_in[3];
  const float* ebhh = (const float*)d_in[4];
  // d_in[5..8] enc layer 1: dead (only feeds dead decoder layer 1)
  const float* dWih = (const float*)d_in[9];   // dec_Wih0
  const float* dWhh = (const float*)d_in[10];  // dec_Whh0
  const float* dbih = (const float*)d_in[11];
  const float* dbhh = (const float*)d_in[12];
  // d_in[13..16] dec layer 1: dead (hB/cB never reach outs)
  const float* Wo   = (const float*)d_in[17];  // [32,512]
  const float* bo   = (const float*)d_in[18];  // [32]
  float* out = (float*)d_out;

  u32* pubbuf = (u32*)d_ws;                    // [2][PODS][BT][HH] tagged h (u32)

  hipFuncSetAttribute(reinterpret_cast<const void*>(lstm_ae_kernel),
                      hipFuncAttributeMaxDynamicSharedMemorySize, LDS_BYTES);

  init_ws_kernel<<<dim3((PUB_U32 + NTHR - 1) / NTHR), dim3(NTHR), 0, stream>>>(pubbuf);
  lstm_ae_kernel<<<dim3(NBLK), dim3(NTHR), LDS_BYTES, stream>>>(
      x, eWih, eWhh, ebih, ebhh, dWih, dWhh, dbih, dbhh, Wo, bo,
      out, pubbuf);
}